// Round 6
// baseline (295.907 us; speedup 1.0000x reference)
//
#include <hip/hip_runtime.h>

// x: [B=2, C=3, D=128, H=160, W=160] fp32, num_steps=6
#define BB 2
#define DD 128
#define HH 160
#define WW 160
constexpr int S   = DD * HH * WW;    // voxels per batch   = 3,276,800
constexpr int PL  = HH * WW;         // plane (h*w)        = 25,600
constexpr int K   = 4;               // consecutive voxels per thread
constexpr int VPB = 256 * K;         // 1024 voxels per block
constexpr int TPP = PL / VPB;        // 25 tiles per plane
constexpr int NT  = BB * DD * TPP;   // 6400 blocks
constexpr int PER_XCD = NT / 8;      // 800 -> 32 contiguous d-planes per XCD

// Cost model (fit rounds 0-5): time ≈ lane-bytes / ~9.3-10.7 B/cyc/CU, invariant to
// locality; wave-granular exec-skip (s_cbranch_execz) is the only free gather.
// {2,2,2} + skips on the two sigma=0.125 sites = 156 B/voxel floor. This round:
// pack all stream accesses to dwordx4 (4 consecutive voxels/thread) to remove any
// per-instruction residual (we run at 87% of the memset's byte rate; memset is 16B/lane).

// 12-byte, 4-aligned record: single dwordx3 load/store (gathers only)
struct __attribute__((packed, aligned(4))) f3 { float x, y, z; };

// clamp(round(base + flow)) per dim; returns clamped coords + linear index
__device__ __forceinline__ void clamp_idx(int d, int h, int w,
                                          float f0, float f1, float f2,
                                          int& od, int& oh, int& ow, int& lin) {
    od = (int)fminf(fmaxf(rintf((float)d + f0), 0.0f), (float)(DD - 1));
    oh = (int)fminf(fmaxf(rintf((float)h + f1), 0.0f), (float)(HH - 1));
    ow = (int)fminf(fmaxf(rintf((float)w + f2), 0.0f), (float)(WW - 1));
    lin = (od * HH + oh) * WW + ow;
}

template <bool SOA>
__device__ __forceinline__ void gath3(const float* __restrict__ v, int b, int idx,
                                      float scale, float* o) {
    if constexpr (SOA) {
        const float* p = v + b * 3 * S + idx;
        o[0] = p[0] * scale; o[1] = p[S] * scale; o[2] = p[2 * S] * scale;
    } else {
        f3 t = *(const f3*)(v + (b * S + idx) * 3);
        o[0] = t.x; o[1] = t.y; o[2] = t.z;
    }
}

// TWO squaring steps fused:  v''(p) = v'(p) + v'(r1),  v'(q) = v(q) + v(r).
// M0/M2 mask the two sigma_base jump sites (wave-skippable only when sigma=0.125,
// i.e. kernel 1); the middle site jumps by 2*sigma_base and is never skippable.
template <bool IN_SOA, bool OUT_SOA, bool M0, bool M2>
__global__ __launch_bounds__(256) void fused2_k(const float* __restrict__ vin,
                                                float* __restrict__ vout,
                                                float scale) {
    // XCD-aware swizzle: each XCD owns a contiguous 1/8 slab (32 d-planes).
    int t  = blockIdx.x;
    int nb = (t >> 3) + (t & 7) * PER_XCD;
    int b  = nb / (DD * TPP);
    int r  = nb - b * (DD * TPP);
    int d  = r / TPP;
    int ip0 = (r - d * TPP) * VPB + threadIdx.x * 4;  // 4 consecutive voxels
    int p0  = d * PL + ip0;

    // --- stage 1: center reads, packed dwordx4 (fully coalesced: 64 lanes x 16B) ---
    float a[K][3];
    if constexpr (IN_SOA) {
        float4 A = *(const float4*)(vin + b * 3 * S + p0);          // channel 0
        float4 B = *(const float4*)(vin + b * 3 * S + S + p0);      // channel 1
        float4 C = *(const float4*)(vin + b * 3 * S + 2 * S + p0);  // channel 2
        a[0][0] = A.x * scale; a[1][0] = A.y * scale; a[2][0] = A.z * scale; a[3][0] = A.w * scale;
        a[0][1] = B.x * scale; a[1][1] = B.y * scale; a[2][1] = B.z * scale; a[3][1] = B.w * scale;
        a[0][2] = C.x * scale; a[1][2] = C.y * scale; a[2][2] = C.z * scale; a[3][2] = C.w * scale;
    } else {
        const float4* q = (const float4*)(vin + (b * S + p0) * 3);  // 48B = 3 x dwordx4
        float4 A = q[0], B = q[1], C = q[2];
        a[0][0] = A.x; a[0][1] = A.y; a[0][2] = A.z;
        a[1][0] = A.w; a[1][1] = B.x; a[1][2] = B.y;
        a[2][0] = B.z; a[2][1] = B.w; a[2][2] = C.x;
        a[3][0] = C.y; a[3][1] = C.z; a[3][2] = C.w;
    }

    int p[K], h[K], w[K];
#pragma unroll
    for (int k = 0; k < K; ++k) {
        int ip = ip0 + k;
        w[k] = ip % WW; h[k] = ip / WW;
        p[k] = p0 + k;
    }

    // --- stage 2: r0 = clamp(round(p + v(p))) ; g = v(r0) ---
    int r0i[K];
#pragma unroll
    for (int k = 0; k < K; ++k) {
        int rd, rh, rw;
        clamp_idx(d, h[k], w[k], a[k][0], a[k][1], a[k][2], rd, rh, rw, r0i[k]);
    }
    float g[K][3];
#pragma unroll
    for (int k = 0; k < K; ++k) {
        if constexpr (M0) {
            if (r0i[k] != p[k]) {
                gath3<IN_SOA>(vin, b, r0i[k], scale, g[k]);
            } else {
                g[k][0] = a[k][0]; g[k][1] = a[k][1]; g[k][2] = a[k][2];
            }
        } else {
            gath3<IN_SOA>(vin, b, r0i[k], scale, g[k]);
        }
    }
    // --- stage 3: v1 = a + g ; r1 = clamp(round(p + v1)) ---
    float v1[K][3];
    int r1d[K], r1h[K], r1w[K], r1i[K];
#pragma unroll
    for (int k = 0; k < K; ++k) {
        v1[k][0] = a[k][0] + g[k][0];
        v1[k][1] = a[k][1] + g[k][1];
        v1[k][2] = a[k][2] + g[k][2];
        clamp_idx(d, h[k], w[k], v1[k][0], v1[k][1], v1[k][2],
                  r1d[k], r1h[k], r1w[k], r1i[k]);
    }
    // --- stage 4: bb = v(r1), unmasked (never wave-skippable) ---
    float bb[K][3];
#pragma unroll
    for (int k = 0; k < K; ++k)
        gath3<IN_SOA>(vin, b, r1i[k], scale, bb[k]);
    // --- stage 5: r2 = clamp(round(r1 + bb)) ; h2 = v(r2) ---
    int r2i[K];
#pragma unroll
    for (int k = 0; k < K; ++k) {
        int rd, rh, rw;
        clamp_idx(r1d[k], r1h[k], r1w[k], bb[k][0], bb[k][1], bb[k][2],
                  rd, rh, rw, r2i[k]);
    }
    float h2[K][3];
#pragma unroll
    for (int k = 0; k < K; ++k) {
        if constexpr (M2) {
            if (r2i[k] != r1i[k]) {
                gath3<IN_SOA>(vin, b, r2i[k], scale, h2[k]);
            } else {
                h2[k][0] = bb[k][0]; h2[k][1] = bb[k][1]; h2[k][2] = bb[k][2];
            }
        } else {
            gath3<IN_SOA>(vin, b, r2i[k], scale, h2[k]);
        }
    }
    // --- stage 6: out = v1 + (bb + h2) [ref grouping]; packed dwordx4 stores ---
    float o[K][3];
#pragma unroll
    for (int k = 0; k < K; ++k) {
        o[k][0] = v1[k][0] + (bb[k][0] + h2[k][0]);
        o[k][1] = v1[k][1] + (bb[k][1] + h2[k][1]);
        o[k][2] = v1[k][2] + (bb[k][2] + h2[k][2]);
    }
    if constexpr (OUT_SOA) {
        *(float4*)(vout + b * 3 * S + p0)         = float4{o[0][0], o[1][0], o[2][0], o[3][0]};
        *(float4*)(vout + b * 3 * S + S + p0)     = float4{o[0][1], o[1][1], o[2][1], o[3][1]};
        *(float4*)(vout + b * 3 * S + 2 * S + p0) = float4{o[0][2], o[1][2], o[2][2], o[3][2]};
    } else {
        float4* q = (float4*)(vout + (b * S + p0) * 3);
        q[0] = float4{o[0][0], o[0][1], o[0][2], o[1][0]};
        q[1] = float4{o[1][1], o[1][2], o[2][0], o[2][1]};
        q[2] = float4{o[2][2], o[3][0], o[3][1], o[3][2]};
    }
}

extern "C" void kernel_launch(void* const* d_in, const int* in_sizes, int n_in,
                              void* d_out, int out_size, void* d_ws, size_t ws_size,
                              hipStream_t stream) {
    const float* x = (const float*)d_in[0];
    float* out = (float*)d_out;     // 78,643,200 bytes — doubles as AoS intermediate
    float* ws  = (float*)d_ws;      // >= 78,643,200 bytes (tight AoS)

    // {2,2,2}: bytes-optimal schedule. Masks only where waves actually skip
    // (kernel 1's two sigma=0.125 sites).
    fused2_k<true,  false, true,  true ><<<NT, 256, 0, stream>>>(x,   out, 1.0f / 64.0f); // steps 1-2
    fused2_k<false, false, false, false><<<NT, 256, 0, stream>>>(out, ws,  1.0f);         // steps 3-4
    fused2_k<false, true,  false, false><<<NT, 256, 0, stream>>>(ws,  out, 1.0f);         // steps 5-6
}